// Round 1
// baseline (448.206 us; speedup 1.0000x reference)
//
#include <hip/hip_runtime.h>
#include <math.h>

// Problem shape (fixed by setup_inputs): logits [8,12,256,256] fp32, targets [8,256,256] i32.
constexpr int B_  = 8;
constexpr int C_  = 12;
constexpr int H_  = 256;
constexpr int W_  = 256;
constexpr int HW_ = H_ * W_;
constexpr int NBC_ = B_ * C_;           // 96
constexpr float BIGF = 1e6f;            // reference sentinel

// ---------------------------------------------------------------------------
// K0: has_fg[bc] = any(targets[b] == c)
// ---------------------------------------------------------------------------
__global__ void k_hasfg(const int* __restrict__ t, int* __restrict__ hasfg) {
    int bc = blockIdx.x;
    int b = bc / C_;
    int c = bc - b * C_;
    const int* tb = t + b * HW_;
    int found = 0;
    for (int i = threadIdx.x; i < HW_; i += blockDim.x)
        found |= (tb[i] == c) ? 1 : 0;
    __shared__ int s;
    if (threadIdx.x == 0) s = 0;
    __syncthreads();
    if (found) atomicOr(&s, 1);
    __syncthreads();
    if (threadIdx.x == 0) hasfg[bc] = s;
}

// ---------------------------------------------------------------------------
// K1: vertical EDT scans. One thread per (bc, w) column.
// Down scan writes partial distance (ih - last_zero_above, sentinel -BIG),
// then the same thread up-scans, takes min with (next_zero_below - ih,
// sentinel +BIG), clamps at BIG and squares — exactly the reference's
// cummax formulation. pos EDT: zeros are (t != c). neg EDT: zeros are (t == c).
// ---------------------------------------------------------------------------
__global__ void k_vert(const int* __restrict__ t,
                       float* __restrict__ g2p, float* __restrict__ g2n) {
    int idx = blockIdx.x * blockDim.x + threadIdx.x;   // bc*W + w
    if (idx >= NBC_ * W_) return;
    int w = idx & (W_ - 1);
    int bc = idx >> 8;                                  // / W_
    int b = bc / C_;
    int c = bc - b * C_;
    const int* tcol = t + b * HW_ + w;
    float* gp = g2p + bc * HW_ + w;
    float* gn = g2n + bc * HW_ + w;

    // down scan: store partial (fh - last_zero_at_or_above)
    float last_neq = -BIGF;   // last h with t != c  (zero pixel for pos EDT)
    float last_eq  = -BIGF;   // last h with t == c  (zero pixel for neg EDT)
    #pragma unroll 4
    for (int h = 0; h < H_; ++h) {
        int tv = tcol[h * W_];
        float fh = (float)h;
        if (tv == c) last_eq = fh; else last_neq = fh;
        gp[h * W_] = fh - last_neq;
        gn[h * W_] = fh - last_eq;
    }
    // up scan: finalize g = min(partial, next_zero_below - fh); clamp; square
    float next_neq = BIGF;
    float next_eq  = BIGF;
    #pragma unroll 4
    for (int h = H_ - 1; h >= 0; --h) {
        int tv = tcol[h * W_];
        float fh = (float)h;
        if (tv == c) next_eq = fh; else next_neq = fh;
        float g1 = fminf(gp[h * W_], next_neq - fh);
        float g2 = fminf(gn[h * W_], next_eq - fh);
        g1 = fminf(g1, BIGF);
        g2 = fminf(g2, BIGF);
        gp[h * W_] = g1 * g1;
        gn[h * W_] = g2 * g2;
    }
}

// ---------------------------------------------------------------------------
// K2: horizontal brute-force min-plus parabola pass (matches reference's
// exact min over all k). One wave per row (bc,h); 4 waves per block.
// Each lane owns 4 output columns j = lane + 64*i. Rows staged in LDS
// (broadcast reads, conflict-free). dt = has_fg ? sqrt(neg)-sqrt(pos) : 0.
// ---------------------------------------------------------------------------
__global__ void k_horiz(const float* __restrict__ g2p, const float* __restrict__ g2n,
                        const int* __restrict__ hasfg, float* __restrict__ dt) {
    __shared__ float sp[4][W_];
    __shared__ float sn[4][W_];
    int wave = threadIdx.x >> 6;
    int lane = threadIdx.x & 63;
    int row = blockIdx.x * 4 + wave;       // in [0, NBC*H)
    int bc = row >> 8;                      // / H_
    const float* gp = g2p + row * W_;
    const float* gn = g2n + row * W_;
    for (int i = lane; i < W_; i += 64) {
        sp[wave][i] = gp[i];
        sn[wave][i] = gn[i];
    }
    __syncthreads();

    float bp[4], bn[4], dj[4];
    #pragma unroll
    for (int i = 0; i < 4; ++i) {
        bp[i] = 3.4e38f;
        bn[i] = 3.4e38f;
        dj[i] = (float)(lane + 64 * i);    // running (j - k), decremented per k
    }
    #pragma unroll 2
    for (int k = 0; k < W_; ++k) {
        float vp = sp[wave][k];
        float vn = sn[wave][k];
        #pragma unroll
        for (int i = 0; i < 4; ++i) {
            float d = dj[i];
            bp[i] = fminf(bp[i], fmaf(d, d, vp));
            bn[i] = fminf(bn[i], fmaf(d, d, vn));
            dj[i] = d - 1.0f;
        }
    }
    int hf = hasfg[bc];
    float* drow = dt + row * W_;
    #pragma unroll
    for (int i = 0; i < 4; ++i) {
        float v = hf ? (sqrtf(bn[i]) - sqrtf(bp[i])) : 0.0f;
        drow[lane + 64 * i] = v;
    }
}

// ---------------------------------------------------------------------------
// K3: per-(bc) min/max of dt -> normalization params {dmin, 1/(dmax-dmin+1e-8)}
// ---------------------------------------------------------------------------
__global__ void k_minmax(const float* __restrict__ dt, float* __restrict__ norm) {
    int bc = blockIdx.x;
    const float* d = dt + bc * HW_;
    float mn = 3.4e38f, mx = -3.4e38f;
    for (int i = threadIdx.x; i < HW_; i += blockDim.x) {
        float v = d[i];
        mn = fminf(mn, v);
        mx = fmaxf(mx, v);
    }
    #pragma unroll
    for (int off = 32; off; off >>= 1) {
        mn = fminf(mn, __shfl_down(mn, off));
        mx = fmaxf(mx, __shfl_down(mx, off));
    }
    __shared__ float smn[4], smx[4];
    int wave = threadIdx.x >> 6, lane = threadIdx.x & 63;
    if (lane == 0) { smn[wave] = mn; smx[wave] = mx; }
    __syncthreads();
    if (threadIdx.x == 0) {
        float a = smn[0], b = smx[0];
        for (int i = 1; i < 4; ++i) { a = fminf(a, smn[i]); b = fmaxf(b, smx[i]); }
        norm[bc * 2]     = a;
        norm[bc * 2 + 1] = 1.0f / (b - a + 1e-8f);
    }
}

// ---------------------------------------------------------------------------
// K4: fused softmax over C + per-(b,c) sums of probs*dtn, probs^2, dtn^2.
// accum[bc*3 + {0,1,2}] must be pre-zeroed.
// ---------------------------------------------------------------------------
__global__ void k_sums(const float* __restrict__ logits, const float* __restrict__ dt,
                       const float* __restrict__ norm, float* __restrict__ accum) {
    int b = blockIdx.y;
    __shared__ float snorm[C_ * 2];
    if (threadIdx.x < C_ * 2) snorm[threadIdx.x] = norm[b * C_ * 2 + threadIdx.x];
    __syncthreads();

    const float* lb = logits + b * C_ * HW_;
    const float* db = dt + b * C_ * HW_;

    float inter[C_], p2[C_], d2s[C_];
    #pragma unroll
    for (int c = 0; c < C_; ++c) { inter[c] = 0.f; p2[c] = 0.f; d2s[c] = 0.f; }

    for (int p = blockIdx.x * blockDim.x + threadIdx.x; p < HW_;
         p += gridDim.x * blockDim.x) {
        float l[C_];
        float mx = -3.4e38f;
        #pragma unroll
        for (int c = 0; c < C_; ++c) { l[c] = lb[c * HW_ + p]; mx = fmaxf(mx, l[c]); }
        float s = 0.f;
        #pragma unroll
        for (int c = 0; c < C_; ++c) { l[c] = expf(l[c] - mx); s += l[c]; }
        float inv = 1.0f / s;
        #pragma unroll
        for (int c = 0; c < C_; ++c) {
            float pr = l[c] * inv;
            float dv = db[c * HW_ + p];
            float dn = (dv - snorm[c * 2]) * snorm[c * 2 + 1];
            inter[c] = fmaf(pr, dn, inter[c]);
            p2[c]    = fmaf(pr, pr, p2[c]);
            d2s[c]   = fmaf(dn, dn, d2s[c]);
        }
    }

    int lane = threadIdx.x & 63;
    #pragma unroll
    for (int c = 0; c < C_; ++c) {
        float a = inter[c], p = p2[c], d = d2s[c];
        #pragma unroll
        for (int off = 32; off; off >>= 1) {
            a += __shfl_down(a, off);
            p += __shfl_down(p, off);
            d += __shfl_down(d, off);
        }
        if (lane == 0) {
            atomicAdd(&accum[(b * C_ + c) * 3 + 0], a);
            atomicAdd(&accum[(b * C_ + c) * 3 + 1], p);
            atomicAdd(&accum[(b * C_ + c) * 3 + 2], d);
        }
    }
}

// ---------------------------------------------------------------------------
// K5: dice per (b,c), mean of (1 - dice) -> out[0]
// ---------------------------------------------------------------------------
__global__ void k_final(const float* __restrict__ accum, float* __restrict__ out) {
    int tid = threadIdx.x;
    float v = 0.f;
    if (tid < NBC_) {
        float inter = accum[tid * 3 + 0];
        float p2    = accum[tid * 3 + 1];
        float d2    = accum[tid * 3 + 2];
        float dice = 2.0f * inter / (p2 + d2 + 1e-6f);
        v = 1.0f - dice;
    }
    #pragma unroll
    for (int off = 32; off; off >>= 1) v += __shfl_down(v, off);
    __shared__ float s2[2];
    if ((tid & 63) == 0) s2[tid >> 6] = v;
    __syncthreads();
    if (tid == 0) out[0] = (s2[0] + s2[1]) / (float)NBC_;
}

// ---------------------------------------------------------------------------
extern "C" void kernel_launch(void* const* d_in, const int* in_sizes, int n_in,
                              void* d_out, int out_size, void* d_ws, size_t ws_size,
                              hipStream_t stream) {
    const float* logits  = (const float*)d_in[0];
    const int*   targets = (const int*)d_in[1];
    float* out = (float*)d_out;

    // workspace layout (fp32): g2_pos | g2_neg | dt | norm[96*2] | accum[96*3] | hasfg[96]
    float* g2p   = (float*)d_ws;
    float* g2n   = g2p + (size_t)NBC_ * HW_;
    float* dt    = g2n + (size_t)NBC_ * HW_;
    float* norm  = dt  + (size_t)NBC_ * HW_;
    float* accum = norm + NBC_ * 2;
    int*   hasfg = (int*)(accum + NBC_ * 3);

    hipMemsetAsync(accum, 0, NBC_ * 3 * sizeof(float), stream);

    k_hasfg<<<NBC_, 256, 0, stream>>>(targets, hasfg);
    k_vert<<<(NBC_ * W_ + 255) / 256, 256, 0, stream>>>(targets, g2p, g2n);
    k_horiz<<<NBC_ * H_ / 4, 256, 0, stream>>>(g2p, g2n, hasfg, dt);
    k_minmax<<<NBC_, 256, 0, stream>>>(dt, norm);
    k_sums<<<dim3(32, B_), 256, 0, stream>>>(logits, dt, norm, accum);
    k_final<<<1, 128, 0, stream>>>(accum, out);
}

// Round 2
// 357.397 us; speedup vs baseline: 1.2541x; 1.2541x over previous
//
#include <hip/hip_runtime.h>
#include <math.h>

// Problem shape (fixed by setup_inputs): logits [8,12,256,256] fp32, targets [8,256,256] i32.
constexpr int B_  = 8;
constexpr int C_  = 12;
constexpr int H_  = 256;
constexpr int W_  = 256;
constexpr int HW_ = H_ * W_;
constexpr int NBC_ = B_ * C_;           // 96
constexpr float BIGF = 1e6f;            // reference sentinel

// Order-preserving float<->uint encoding for atomic min/max on signed floats.
__device__ inline unsigned encf(float f) {
    unsigned u = __float_as_uint(f);
    return (u & 0x80000000u) ? ~u : (u | 0x80000000u);
}
__device__ inline float decf(unsigned e) {
    return (e & 0x80000000u) ? __uint_as_float(e & 0x7FFFFFFFu) : __uint_as_float(~e);
}

// ---------------------------------------------------------------------------
// K1: vertical EDT scans, segmented for occupancy.
// Block = 256 threads = 32 columns x 8 segments (32 rows each); 768 blocks.
// Phase A: per-segment summaries (last/first eq/neq) -> LDS.
// Phase B: carries = prefix/suffix of summaries across segments.
// Phase C: in-register re-scan (targets kept packed as bytes), write g^2.
// Exactly matches reference cummax formulation: sentinels +-1e6, clamp at
// 1e6, then square. Also fuses has_fg via atomicOr (hasfg pre-zeroed).
// ---------------------------------------------------------------------------
__global__ void k_vert(const int* __restrict__ t,
                       float* __restrict__ g2p, float* __restrict__ g2n,
                       int* __restrict__ hasfg) {
    constexpr int SEG = 8, SH = 32;
    int tid = threadIdx.x;
    int s  = tid >> 5;          // segment
    int wl = tid & 31;          // column within tile
    int blk = blockIdx.x;       // 96*8
    int bc = blk >> 3;
    int w0 = (blk & 7) * 32;
    int b = bc / C_, c = bc - b * C_;
    int w = w0 + wl;
    const int* base = t + b * HW_ + w;
    int h0 = s * SH;

    // Phase A: load targets (keep packed 4 per reg), segment summaries.
    unsigned tp[SH / 4];
    int lastEq = -1, lastNeq = -1, firstEq = 256, firstNeq = 256;
    #pragma unroll 8
    for (int i = 0; i < SH; ++i) {
        int tv = base[(h0 + i) * W_];
        if ((i & 3) == 0) tp[i >> 2] = 0;
        tp[i >> 2] |= (unsigned)tv << ((i & 3) * 8);
        int h = h0 + i;
        if (tv == c) { lastEq = h;  if (firstEq  == 256) firstEq  = h; }
        else         { lastNeq = h; if (firstNeq == 256) firstNeq = h; }
    }
    __shared__ int sLE[SEG][32], sLN[SEG][32], sFE[SEG][32], sFN[SEG][32];
    sLE[s][wl] = lastEq; sLN[s][wl] = lastNeq;
    sFE[s][wl] = firstEq; sFN[s][wl] = firstNeq;
    __syncthreads();

    // Phase B: carries across segments.
    int carLE = -1, carLN = -1;
    for (int q = 0; q < s; ++q) {
        carLE = max(carLE, sLE[q][wl]);
        carLN = max(carLN, sLN[q][wl]);
    }
    int carFE = 256, carFN = 256;
    for (int q = s + 1; q < SEG; ++q) {
        carFE = min(carFE, sFE[q][wl]);
        carFN = min(carFN, sFN[q][wl]);
    }
    if (s == SEG - 1) {
        if (max(carLE, lastEq) >= 0) atomicOr(&hasfg[bc], 1);
    }

    // Phase C forward: per-element last-zero indices (kept in registers).
    int pLE[SH], pLN[SH];
    {
        int le = carLE, ln = carLN;
        #pragma unroll
        for (int i = 0; i < SH; ++i) {
            int tv = (tp[i >> 2] >> ((i & 3) * 8)) & 0xFF;
            int h = h0 + i;
            if (tv == c) le = h; else ln = h;
            pLE[i] = le; pLN[i] = ln;
        }
    }
    // Phase C backward: combine with next-zero, clamp, square, store.
    {
        int fe = carFE, fn = carFN;
        float* gp = g2p + (size_t)bc * HW_ + w;
        float* gn = g2n + (size_t)bc * HW_ + w;
        #pragma unroll
        for (int i = SH - 1; i >= 0; --i) {
            int tv = (tp[i >> 2] >> ((i & 3) * 8)) & 0xFF;
            int h = h0 + i;
            if (tv == c) fe = h; else fn = h;
            float fh = (float)h;
            // pos EDT: zeros where t != c
            float lNq = (pLN[i] < 0) ? -BIGF : (float)pLN[i];
            float nNq = (fn > 255) ? BIGF : (float)fn;
            float g1 = fminf(fminf(fh - lNq, nNq - fh), BIGF);
            // neg EDT: zeros where t == c
            float lEq = (pLE[i] < 0) ? -BIGF : (float)pLE[i];
            float nEq = (fe > 255) ? BIGF : (float)fe;
            float g2 = fminf(fminf(fh - lEq, nEq - fh), BIGF);
            gp[h * W_] = g1 * g1;
            gn[h * W_] = g2 * g2;
        }
    }
}

// ---------------------------------------------------------------------------
// K2: horizontal exact min-plus parabola via expanding-radius search.
// One wave per row, 4 rows (same bc) per block. best[j] starts at k=j; scan
// k=j+-r outward, stop (wave-uniform) when r^2 >= best for every lane ---
// exact since all remaining candidates are >= r^2. fmaf(r,r,g2) rounds
// identically to the reference's (j-k)^2 + g2 (product exact, single round).
// Fuses per-bc min/max via encoded atomics. Skips work when has_fg==0
// (dt==0 there, matching reference's gating).
// ---------------------------------------------------------------------------
__global__ void k_horiz(const float* __restrict__ g2p, const float* __restrict__ g2n,
                        const int* __restrict__ hasfg, float* __restrict__ dt,
                        unsigned* __restrict__ umn, unsigned* __restrict__ umx) {
    __shared__ float sp[4][W_];
    __shared__ float sn[4][W_];
    int wave = threadIdx.x >> 6;
    int lane = threadIdx.x & 63;
    int row = blockIdx.x * 4 + wave;       // [0, NBC*H); all 4 rows same bc
    int bc = row >> 8;
    float* drow = dt + (size_t)row * W_;
    int hf = hasfg[bc];                    // uniform across block

    if (!hf) {
        #pragma unroll
        for (int i = 0; i < 4; ++i) drow[lane + 64 * i] = 0.0f;
        if (lane == 0) {
            atomicMin(&umn[bc], encf(0.0f));
            atomicMax(&umx[bc], encf(0.0f));
        }
        return;
    }

    // stage row into LDS (float4 loads, b128 LDS writes)
    ((float4*)sp[wave])[lane] = ((const float4*)(g2p + (size_t)row * W_))[lane];
    ((float4*)sn[wave])[lane] = ((const float4*)(g2n + (size_t)row * W_))[lane];
    __syncthreads();

    float bp[4], bn[4];
    #pragma unroll
    for (int i = 0; i < 4; ++i) {
        int j = lane + 64 * i;
        bp[i] = sp[wave][j];
        bn[i] = sn[wave][j];
    }
    // neg transform expanding search
    for (int r = 1; r < W_; ++r) {
        float fr = (float)r;
        float r2 = fr * fr;
        float m = fmaxf(fmaxf(bn[0], bn[1]), fmaxf(bn[2], bn[3]));
        if (!__any(r2 < m)) break;
        #pragma unroll
        for (int i = 0; i < 4; ++i) {
            int j = lane + 64 * i;
            int kl = j - r, kr = j + r;
            float vl = sn[wave][max(kl, 0)];
            float vr = sn[wave][min(kr, W_ - 1)];
            vl = (kl >= 0) ? vl : 3.0e38f;
            vr = (kr < W_) ? vr : 3.0e38f;
            bn[i] = fminf(bn[i], fmaf(fr, fr, vl));
            bn[i] = fminf(bn[i], fmaf(fr, fr, vr));
        }
    }
    // pos transform expanding search
    for (int r = 1; r < W_; ++r) {
        float fr = (float)r;
        float r2 = fr * fr;
        float m = fmaxf(fmaxf(bp[0], bp[1]), fmaxf(bp[2], bp[3]));
        if (!__any(r2 < m)) break;
        #pragma unroll
        for (int i = 0; i < 4; ++i) {
            int j = lane + 64 * i;
            int kl = j - r, kr = j + r;
            float vl = sp[wave][max(kl, 0)];
            float vr = sp[wave][min(kr, W_ - 1)];
            vl = (kl >= 0) ? vl : 3.0e38f;
            vr = (kr < W_) ? vr : 3.0e38f;
            bp[i] = fminf(bp[i], fmaf(fr, fr, vl));
            bp[i] = fminf(bp[i], fmaf(fr, fr, vr));
        }
    }

    float dval[4], mn = 3.4e38f, mx = -3.4e38f;
    #pragma unroll
    for (int i = 0; i < 4; ++i) {
        dval[i] = sqrtf(bn[i]) - sqrtf(bp[i]);
        mn = fminf(mn, dval[i]);
        mx = fmaxf(mx, dval[i]);
    }
    #pragma unroll
    for (int off = 32; off; off >>= 1) {
        mn = fminf(mn, __shfl_xor(mn, off));
        mx = fmaxf(mx, __shfl_xor(mx, off));
    }
    if (lane == 0) {
        atomicMin(&umn[bc], encf(mn));
        atomicMax(&umx[bc], encf(mx));
    }
    #pragma unroll
    for (int i = 0; i < 4; ++i) drow[lane + 64 * i] = dval[i];
}

// ---------------------------------------------------------------------------
// K3: fused softmax over C + per-(b,c) sums of probs*dtn, probs^2, dtn^2.
// Decodes normalization params from encoded min/max. accum pre-zeroed.
// ---------------------------------------------------------------------------
__global__ void k_sums(const float* __restrict__ logits, const float* __restrict__ dt,
                       const unsigned* __restrict__ umn, const unsigned* __restrict__ umx,
                       float* __restrict__ accum) {
    int b = blockIdx.y;
    __shared__ float snorm[C_ * 2];
    if (threadIdx.x < C_) {
        float mn = decf(umn[b * C_ + threadIdx.x]);
        float mx = decf(umx[b * C_ + threadIdx.x]);
        snorm[threadIdx.x * 2]     = mn;
        snorm[threadIdx.x * 2 + 1] = 1.0f / (mx - mn + 1e-8f);
    }
    __syncthreads();

    const float* lb = logits + (size_t)b * C_ * HW_;
    const float* db = dt + (size_t)b * C_ * HW_;

    float inter[C_], p2[C_], d2s[C_];
    #pragma unroll
    for (int c = 0; c < C_; ++c) { inter[c] = 0.f; p2[c] = 0.f; d2s[c] = 0.f; }

    for (int p = blockIdx.x * blockDim.x + threadIdx.x; p < HW_;
         p += gridDim.x * blockDim.x) {
        float l[C_];
        float mxl = -3.4e38f;
        #pragma unroll
        for (int c = 0; c < C_; ++c) { l[c] = lb[c * HW_ + p]; mxl = fmaxf(mxl, l[c]); }
        float s = 0.f;
        #pragma unroll
        for (int c = 0; c < C_; ++c) { l[c] = expf(l[c] - mxl); s += l[c]; }
        float inv = 1.0f / s;
        #pragma unroll
        for (int c = 0; c < C_; ++c) {
            float pr = l[c] * inv;
            float dv = db[c * HW_ + p];
            float dn = (dv - snorm[c * 2]) * snorm[c * 2 + 1];
            inter[c] = fmaf(pr, dn, inter[c]);
            p2[c]    = fmaf(pr, pr, p2[c]);
            d2s[c]   = fmaf(dn, dn, d2s[c]);
        }
    }

    int lane = threadIdx.x & 63;
    #pragma unroll
    for (int c = 0; c < C_; ++c) {
        float a = inter[c], p = p2[c], d = d2s[c];
        #pragma unroll
        for (int off = 32; off; off >>= 1) {
            a += __shfl_down(a, off);
            p += __shfl_down(p, off);
            d += __shfl_down(d, off);
        }
        if (lane == 0) {
            atomicAdd(&accum[(b * C_ + c) * 3 + 0], a);
            atomicAdd(&accum[(b * C_ + c) * 3 + 1], p);
            atomicAdd(&accum[(b * C_ + c) * 3 + 2], d);
        }
    }
}

// ---------------------------------------------------------------------------
// K4: dice per (b,c), mean of (1 - dice) -> out[0]
// ---------------------------------------------------------------------------
__global__ void k_final(const float* __restrict__ accum, float* __restrict__ out) {
    int tid = threadIdx.x;
    float v = 0.f;
    if (tid < NBC_) {
        float inter = accum[tid * 3 + 0];
        float p2    = accum[tid * 3 + 1];
        float d2    = accum[tid * 3 + 2];
        float dice = 2.0f * inter / (p2 + d2 + 1e-6f);
        v = 1.0f - dice;
    }
    #pragma unroll
    for (int off = 32; off; off >>= 1) v += __shfl_down(v, off);
    __shared__ float s2[2];
    if ((tid & 63) == 0) s2[tid >> 6] = v;
    __syncthreads();
    if (tid == 0) out[0] = (s2[0] + s2[1]) / (float)NBC_;
}

// ---------------------------------------------------------------------------
extern "C" void kernel_launch(void* const* d_in, const int* in_sizes, int n_in,
                              void* d_out, int out_size, void* d_ws, size_t ws_size,
                              hipStream_t stream) {
    const float* logits  = (const float*)d_in[0];
    const int*   targets = (const int*)d_in[1];
    float* out = (float*)d_out;

    // workspace layout (fp32 slots): g2p | g2n | dt | umn[96] | umx[96] | accum[288] | hasfg[96]
    float* g2p   = (float*)d_ws;
    float* g2n   = g2p + (size_t)NBC_ * HW_;
    float* dt    = g2n + (size_t)NBC_ * HW_;
    unsigned* umn = (unsigned*)(dt + (size_t)NBC_ * HW_);
    unsigned* umx = umn + NBC_;
    float* accum = (float*)(umx + NBC_);
    int*   hasfg = (int*)(accum + NBC_ * 3);

    hipMemsetAsync(umn, 0xFF, NBC_ * sizeof(unsigned), stream);
    hipMemsetAsync(umx, 0x00, NBC_ * sizeof(unsigned), stream);
    hipMemsetAsync(accum, 0, NBC_ * 3 * sizeof(float), stream);
    hipMemsetAsync(hasfg, 0, NBC_ * sizeof(int), stream);

    k_vert<<<NBC_ * 8, 256, 0, stream>>>(targets, g2p, g2n, hasfg);
    k_horiz<<<NBC_ * H_ / 4, 256, 0, stream>>>(g2p, g2n, hasfg, dt, umn, umx);
    k_sums<<<dim3(64, B_), 256, 0, stream>>>(logits, dt, umn, umx, accum);
    k_final<<<1, 128, 0, stream>>>(accum, out);
}

// Round 3
// 134.850 us; speedup vs baseline: 3.3237x; 2.6503x over previous
//
#include <hip/hip_runtime.h>
#include <math.h>

// Problem shape (fixed by setup_inputs): logits [8,12,256,256] fp32, targets [8,256,256] i32.
constexpr int B_  = 8;
constexpr int C_  = 12;
constexpr int H_  = 256;
constexpr int W_  = 256;
constexpr int HW_ = H_ * W_;
constexpr int NBC_ = B_ * C_;           // 96
constexpr float BIGF = 1e6f;            // reference sentinel
constexpr int SUMX_ = 16;               // k_sums grid.x (partials per image)

// ---------------------------------------------------------------------------
// K1: vertical EDT scans, segmented for occupancy.
// Block = 256 threads = 32 columns x 8 segments (32 rows each); 768 blocks.
// hasfg update is wave-voted: <=1 atomicOr per block (was up to 32/block).
// ---------------------------------------------------------------------------
__global__ void k_vert(const int* __restrict__ t,
                       float* __restrict__ g2p, float* __restrict__ g2n,
                       int* __restrict__ hasfg) {
    constexpr int SEG = 8, SH = 32;
    int tid = threadIdx.x;
    int s  = tid >> 5;          // segment
    int wl = tid & 31;          // column within tile
    int blk = blockIdx.x;       // 96*8
    int bc = blk >> 3;
    int w0 = (blk & 7) * 32;
    int b = bc / C_, c = bc - b * C_;
    int w = w0 + wl;
    const int* base = t + b * HW_ + w;
    int h0 = s * SH;

    // Phase A: load targets (packed 4/reg), segment summaries.
    unsigned tp[SH / 4];
    int lastEq = -1, lastNeq = -1, firstEq = 256, firstNeq = 256;
    #pragma unroll 8
    for (int i = 0; i < SH; ++i) {
        int tv = base[(h0 + i) * W_];
        if ((i & 3) == 0) tp[i >> 2] = 0;
        tp[i >> 2] |= (unsigned)tv << ((i & 3) * 8);
        int h = h0 + i;
        if (tv == c) { lastEq = h;  if (firstEq  == 256) firstEq  = h; }
        else         { lastNeq = h; if (firstNeq == 256) firstNeq = h; }
    }
    __shared__ int sLE[SEG][32], sLN[SEG][32], sFE[SEG][32], sFN[SEG][32];
    sLE[s][wl] = lastEq; sLN[s][wl] = lastNeq;
    sFE[s][wl] = firstEq; sFN[s][wl] = firstNeq;
    __syncthreads();

    // Phase B: carries across segments.
    int carLE = -1, carLN = -1;
    for (int q = 0; q < s; ++q) {
        carLE = max(carLE, sLE[q][wl]);
        carLN = max(carLN, sLN[q][wl]);
    }
    int carFE = 256, carFN = 256;
    for (int q = s + 1; q < SEG; ++q) {
        carFE = min(carFE, sFE[q][wl]);
        carFN = min(carFN, sFN[q][wl]);
    }
    // wave-voted hasfg: only the last wave (s in {6,7}) can have pred true
    bool pred = (s == SEG - 1) && (max(carLE, lastEq) >= 0);
    if (__any(pred) && (tid & 63) == 0) atomicOr(&hasfg[bc], 1);

    // Phase C forward: per-element last-zero indices (registers).
    int pLE[SH], pLN[SH];
    {
        int le = carLE, ln = carLN;
        #pragma unroll
        for (int i = 0; i < SH; ++i) {
            int tv = (tp[i >> 2] >> ((i & 3) * 8)) & 0xFF;
            int h = h0 + i;
            if (tv == c) le = h; else ln = h;
            pLE[i] = le; pLN[i] = ln;
        }
    }
    // Phase C backward: combine with next-zero, clamp, square, store.
    {
        int fe = carFE, fn = carFN;
        float* gp = g2p + (size_t)bc * HW_ + w;
        float* gn = g2n + (size_t)bc * HW_ + w;
        #pragma unroll
        for (int i = SH - 1; i >= 0; --i) {
            int tv = (tp[i >> 2] >> ((i & 3) * 8)) & 0xFF;
            int h = h0 + i;
            if (tv == c) fe = h; else fn = h;
            float fh = (float)h;
            float lNq = (pLN[i] < 0) ? -BIGF : (float)pLN[i];
            float nNq = (fn > 255) ? BIGF : (float)fn;
            float g1 = fminf(fminf(fh - lNq, nNq - fh), BIGF);
            float lEq = (pLE[i] < 0) ? -BIGF : (float)pLE[i];
            float nEq = (fe > 255) ? BIGF : (float)fe;
            float g2 = fminf(fminf(fh - lEq, nEq - fh), BIGF);
            gp[h * W_] = g1 * g1;
            gn[h * W_] = g2 * g2;
        }
    }
}

// ---------------------------------------------------------------------------
// K2: horizontal exact min-plus parabola via expanding-radius search.
// One wave per row, 4 rows (same bc) per block. NO atomics: block-level
// min/max reduced in LDS, written plainly to pmn/pmx[blockIdx].
// ---------------------------------------------------------------------------
__global__ void k_horiz(const float* __restrict__ g2p, const float* __restrict__ g2n,
                        const int* __restrict__ hasfg, float* __restrict__ dt,
                        float* __restrict__ pmn, float* __restrict__ pmx) {
    __shared__ float sp[4][W_];
    __shared__ float sn[4][W_];
    __shared__ float bmn[4], bmx[4];
    int wave = threadIdx.x >> 6;
    int lane = threadIdx.x & 63;
    int row = blockIdx.x * 4 + wave;       // [0, NBC*H); all 4 rows same bc
    int bc = row >> 8;
    float* drow = dt + (size_t)row * W_;
    int hf = hasfg[bc];                    // uniform across block

    if (!hf) {
        #pragma unroll
        for (int i = 0; i < 4; ++i) drow[lane + 64 * i] = 0.0f;
        if (threadIdx.x == 0) { pmn[blockIdx.x] = 0.0f; pmx[blockIdx.x] = 0.0f; }
        return;
    }

    ((float4*)sp[wave])[lane] = ((const float4*)(g2p + (size_t)row * W_))[lane];
    ((float4*)sn[wave])[lane] = ((const float4*)(g2n + (size_t)row * W_))[lane];
    __syncthreads();

    float bp[4], bn[4];
    #pragma unroll
    for (int i = 0; i < 4; ++i) {
        int j = lane + 64 * i;
        bp[i] = sp[wave][j];
        bn[i] = sn[wave][j];
    }
    // neg transform expanding search (exact: remaining candidates >= r^2)
    for (int r = 1; r < W_; ++r) {
        float fr = (float)r;
        float r2 = fr * fr;
        float m = fmaxf(fmaxf(bn[0], bn[1]), fmaxf(bn[2], bn[3]));
        if (!__any(r2 < m)) break;
        #pragma unroll
        for (int i = 0; i < 4; ++i) {
            int j = lane + 64 * i;
            int kl = j - r, kr = j + r;
            float vl = sn[wave][max(kl, 0)];
            float vr = sn[wave][min(kr, W_ - 1)];
            vl = (kl >= 0) ? vl : 3.0e38f;
            vr = (kr < W_) ? vr : 3.0e38f;
            bn[i] = fminf(bn[i], fmaf(fr, fr, vl));
            bn[i] = fminf(bn[i], fmaf(fr, fr, vr));
        }
    }
    // pos transform expanding search
    for (int r = 1; r < W_; ++r) {
        float fr = (float)r;
        float r2 = fr * fr;
        float m = fmaxf(fmaxf(bp[0], bp[1]), fmaxf(bp[2], bp[3]));
        if (!__any(r2 < m)) break;
        #pragma unroll
        for (int i = 0; i < 4; ++i) {
            int j = lane + 64 * i;
            int kl = j - r, kr = j + r;
            float vl = sp[wave][max(kl, 0)];
            float vr = sp[wave][min(kr, W_ - 1)];
            vl = (kl >= 0) ? vl : 3.0e38f;
            vr = (kr < W_) ? vr : 3.0e38f;
            bp[i] = fminf(bp[i], fmaf(fr, fr, vl));
            bp[i] = fminf(bp[i], fmaf(fr, fr, vr));
        }
    }

    float dval[4], mn = 3.4e38f, mx = -3.4e38f;
    #pragma unroll
    for (int i = 0; i < 4; ++i) {
        dval[i] = sqrtf(bn[i]) - sqrtf(bp[i]);
        mn = fminf(mn, dval[i]);
        mx = fmaxf(mx, dval[i]);
    }
    #pragma unroll
    for (int off = 32; off; off >>= 1) {
        mn = fminf(mn, __shfl_xor(mn, off));
        mx = fmaxf(mx, __shfl_xor(mx, off));
    }
    if (lane == 0) { bmn[wave] = mn; bmx[wave] = mx; }
    __syncthreads();
    if (threadIdx.x == 0) {
        pmn[blockIdx.x] = fminf(fminf(bmn[0], bmn[1]), fminf(bmn[2], bmn[3]));
        pmx[blockIdx.x] = fmaxf(fmaxf(bmx[0], bmx[1]), fmaxf(bmx[2], bmx[3]));
    }
    #pragma unroll
    for (int i = 0; i < 4; ++i) drow[lane + 64 * i] = dval[i];
}

// ---------------------------------------------------------------------------
// K2b: reduce 64 per-block partials per bc -> norm {dmin, 1/(dmax-dmin+1e-8)}
// ---------------------------------------------------------------------------
__global__ void k_norm(const float* __restrict__ pmn, const float* __restrict__ pmx,
                       float* __restrict__ norm) {
    int bc = blockIdx.x;
    int i = threadIdx.x;                   // 64
    float mn = pmn[bc * 64 + i];
    float mx = pmx[bc * 64 + i];
    #pragma unroll
    for (int off = 32; off; off >>= 1) {
        mn = fminf(mn, __shfl_xor(mn, off));
        mx = fmaxf(mx, __shfl_xor(mx, off));
    }
    if (i == 0) {
        norm[bc * 2]     = mn;
        norm[bc * 2 + 1] = 1.0f / (mx - mn + 1e-8f);
    }
}

// ---------------------------------------------------------------------------
// K3: fused softmax over C + per-(b,c) sums. NO atomics: block partials via
// LDS cross-wave reduce, plain store to accum_p[((b*SUMX+gx)*C + c)*3 + comp].
// ---------------------------------------------------------------------------
__global__ void k_sums(const float* __restrict__ logits, const float* __restrict__ dt,
                       const float* __restrict__ norm, float* __restrict__ accum_p) {
    int b = blockIdx.y;
    __shared__ float snorm[C_ * 2];
    __shared__ float sI[4][C_], sP[4][C_], sD[4][C_];
    if (threadIdx.x < C_ * 2) snorm[threadIdx.x] = norm[b * C_ * 2 + threadIdx.x];
    __syncthreads();

    const float* lb = logits + (size_t)b * C_ * HW_;
    const float* db = dt + (size_t)b * C_ * HW_;

    float inter[C_], p2[C_], d2s[C_];
    #pragma unroll
    for (int c = 0; c < C_; ++c) { inter[c] = 0.f; p2[c] = 0.f; d2s[c] = 0.f; }

    for (int p = blockIdx.x * blockDim.x + threadIdx.x; p < HW_;
         p += gridDim.x * blockDim.x) {
        float l[C_];
        float mxl = -3.4e38f;
        #pragma unroll
        for (int c = 0; c < C_; ++c) { l[c] = lb[c * HW_ + p]; mxl = fmaxf(mxl, l[c]); }
        float s = 0.f;
        #pragma unroll
        for (int c = 0; c < C_; ++c) { l[c] = expf(l[c] - mxl); s += l[c]; }
        float inv = 1.0f / s;
        #pragma unroll
        for (int c = 0; c < C_; ++c) {
            float pr = l[c] * inv;
            float dv = db[c * HW_ + p];
            float dn = (dv - snorm[c * 2]) * snorm[c * 2 + 1];
            inter[c] = fmaf(pr, dn, inter[c]);
            p2[c]    = fmaf(pr, pr, p2[c]);
            d2s[c]   = fmaf(dn, dn, d2s[c]);
        }
    }

    int lane = threadIdx.x & 63;
    int wave = threadIdx.x >> 6;
    #pragma unroll
    for (int c = 0; c < C_; ++c) {
        float a = inter[c], p = p2[c], d = d2s[c];
        #pragma unroll
        for (int off = 32; off; off >>= 1) {
            a += __shfl_down(a, off);
            p += __shfl_down(p, off);
            d += __shfl_down(d, off);
        }
        if (lane == 0) { sI[wave][c] = a; sP[wave][c] = p; sD[wave][c] = d; }
    }
    __syncthreads();
    if (threadIdx.x < C_ * 3) {
        int c = threadIdx.x % C_;
        int comp = threadIdx.x / C_;
        float v = 0.f;
        #pragma unroll
        for (int w = 0; w < 4; ++w)
            v += (comp == 0) ? sI[w][c] : (comp == 1) ? sP[w][c] : sD[w][c];
        accum_p[(((size_t)b * SUMX_ + blockIdx.x) * C_ + c) * 3 + comp] = v;
    }
}

// ---------------------------------------------------------------------------
// K4: reduce partials, dice per (b,c), mean of (1 - dice) -> out[0]
// ---------------------------------------------------------------------------
__global__ void k_final(const float* __restrict__ accum_p, float* __restrict__ out) {
    int tid = threadIdx.x;                 // 128
    float v = 0.f;
    if (tid < NBC_) {
        int b = tid / C_, c = tid - b * C_;
        float inter = 0.f, p2 = 0.f, d2 = 0.f;
        for (int gx = 0; gx < SUMX_; ++gx) {
            size_t base = (((size_t)b * SUMX_ + gx) * C_ + c) * 3;
            inter += accum_p[base];
            p2    += accum_p[base + 1];
            d2    += accum_p[base + 2];
        }
        float dice = 2.0f * inter / (p2 + d2 + 1e-6f);
        v = 1.0f - dice;
    }
    #pragma unroll
    for (int off = 32; off; off >>= 1) v += __shfl_down(v, off);
    __shared__ float s2[2];
    if ((tid & 63) == 0) s2[tid >> 6] = v;
    __syncthreads();
    if (tid == 0) out[0] = (s2[0] + s2[1]) / (float)NBC_;
}

// ---------------------------------------------------------------------------
extern "C" void kernel_launch(void* const* d_in, const int* in_sizes, int n_in,
                              void* d_out, int out_size, void* d_ws, size_t ws_size,
                              hipStream_t stream) {
    const float* logits  = (const float*)d_in[0];
    const int*   targets = (const int*)d_in[1];
    float* out = (float*)d_out;

    // ws layout (fp32 slots): g2p | g2n | dt | pmn[6144] | pmx[6144] |
    //                         norm[192] | accum_p[8*16*12*3] | hasfg[96]
    float* g2p   = (float*)d_ws;
    float* g2n   = g2p + (size_t)NBC_ * HW_;
    float* dt    = g2n + (size_t)NBC_ * HW_;
    float* pmn   = dt  + (size_t)NBC_ * HW_;
    float* pmx   = pmn + NBC_ * 64;
    float* norm  = pmx + NBC_ * 64;
    float* accum = norm + NBC_ * 2;
    int*   hasfg = (int*)(accum + B_ * SUMX_ * C_ * 3);

    hipMemsetAsync(hasfg, 0, NBC_ * sizeof(int), stream);

    k_vert<<<NBC_ * 8, 256, 0, stream>>>(targets, g2p, g2n, hasfg);
    k_horiz<<<NBC_ * H_ / 4, 256, 0, stream>>>(g2p, g2n, hasfg, dt, pmn, pmx);
    k_norm<<<NBC_, 64, 0, stream>>>(pmn, pmx, norm);
    k_sums<<<dim3(SUMX_, B_), 256, 0, stream>>>(logits, dt, norm, accum);
    k_final<<<1, 128, 0, stream>>>(accum, out);
}

// Round 4
// 120.768 us; speedup vs baseline: 3.7113x; 1.1166x over previous
//
#include <hip/hip_runtime.h>
#include <math.h>

// Problem shape (fixed by setup_inputs): logits [8,12,256,256] fp32, targets [8,256,256] i32.
constexpr int B_  = 8;
constexpr int C_  = 12;
constexpr int H_  = 256;
constexpr int W_  = 256;
constexpr int HW_ = H_ * W_;
constexpr int NBC_ = B_ * C_;           // 96
constexpr int SUMX_ = 32;               // k_sums grid.x (partials per image)
constexpr int PAD_ = 256;               // LDS row padding (covers max radius 255)

// Packed vertical-EDT value: bit15 = is_fg (t==c); bits[14:0] = vertical
// distance d to nearest zero of the pixel's own nonzero transform
// (0x7FFF = no zero in column -> reference g = 1e6 - h). The OTHER
// transform's g is always 0 at this pixel, so one u16 encodes both.

// ---------------------------------------------------------------------------
// K1: vertical EDT scans, segmented for occupancy.
// Block = 256 threads = 32 columns x 8 segments (32 rows each); 768 blocks.
// Writes packed u16 (2 B/px instead of 8 B/px) + per-block hasfg flag
// (plain store; k_horiz ORs the 8 w-tile flags). Zero atomics, zero memsets.
// ---------------------------------------------------------------------------
__global__ void k_vert(const int* __restrict__ t,
                       unsigned short* __restrict__ gpk,
                       int* __restrict__ hasfg_p) {
    constexpr int SEG = 8, SH = 32;
    int tid = threadIdx.x;
    int s  = tid >> 5;          // segment
    int wl = tid & 31;          // column within tile
    int blk = blockIdx.x;       // 96*8
    int bc = blk >> 3;
    int w0 = (blk & 7) * 32;
    int b = bc / C_, c = bc - b * C_;
    int w = w0 + wl;
    const int* base = t + b * HW_ + w;
    int h0 = s * SH;

    // Phase A: load targets (packed 4/reg), segment summaries.
    unsigned tp[SH / 4];
    int lastEq = -1, lastNeq = -1, firstEq = 256, firstNeq = 256;
    #pragma unroll 8
    for (int i = 0; i < SH; ++i) {
        int tv = base[(h0 + i) * W_];
        if ((i & 3) == 0) tp[i >> 2] = 0;
        tp[i >> 2] |= (unsigned)tv << ((i & 3) * 8);
        int h = h0 + i;
        if (tv == c) { lastEq = h;  if (firstEq  == 256) firstEq  = h; }
        else         { lastNeq = h; if (firstNeq == 256) firstNeq = h; }
    }
    __shared__ int sLE[SEG][32], sLN[SEG][32], sFE[SEG][32], sFN[SEG][32];
    sLE[s][wl] = lastEq; sLN[s][wl] = lastNeq;
    sFE[s][wl] = firstEq; sFN[s][wl] = firstNeq;
    __syncthreads();

    // Phase B: carries across segments.
    int carLE = -1, carLN = -1;
    for (int q = 0; q < s; ++q) {
        carLE = max(carLE, sLE[q][wl]);
        carLN = max(carLN, sLN[q][wl]);
    }
    int carFE = 256, carFN = 256;
    for (int q = s + 1; q < SEG; ++q) {
        carFE = min(carFE, sFE[q][wl]);
        carFN = min(carFN, sFN[q][wl]);
    }
    // per-block hasfg: s==7 lanes (lanes 32..63 of wave 3) cover full columns
    bool pred = (s == SEG - 1) && (max(carLE, lastEq) >= 0);
    bool anyfg = __any(pred);
    if (tid == 192) hasfg_p[blk] = anyfg ? 1 : 0;

    // Phase C forward: per-element last-zero indices (registers).
    int pLE[SH], pLN[SH];
    {
        int le = carLE, ln = carLN;
        #pragma unroll
        for (int i = 0; i < SH; ++i) {
            int tv = (tp[i >> 2] >> ((i & 3) * 8)) & 0xFF;
            int h = h0 + i;
            if (tv == c) le = h; else ln = h;
            pLE[i] = le; pLN[i] = ln;
        }
    }
    // Phase C backward: pack distance for the pixel's own nonzero transform.
    {
        int fe = carFE, fn = carFN;
        unsigned short* gk = gpk + (size_t)bc * HW_ + w;
        #pragma unroll
        for (int i = SH - 1; i >= 0; --i) {
            int tv = (tp[i >> 2] >> ((i & 3) * 8)) & 0xFF;
            int h = h0 + i;
            if (tv == c) fe = h; else fn = h;
            bool fg = (tv == c);
            // fg pixel: distance to nearest t!=c (pos EDT); bg: to nearest t==c
            int lastZ = fg ? pLN[i] : pLE[i];
            int nextZ = fg ? fn : fe;
            int dl = (lastZ < 0)   ? 0x7FFF : (h - lastZ);
            int dnx = (nextZ > 255) ? 0x7FFF : (nextZ - h);
            int d = min(dl, dnx);
            gk[h * W_] = (unsigned short)(d | (fg ? 0x8000 : 0));
        }
    }
}

// ---------------------------------------------------------------------------
// K2: horizontal exact min-plus parabola via expanding-radius search.
// One wave per row, 4 rows (same bc) per block. LDS rows padded with +inf
// so the inner loop has no bounds clamps; min folded into one fma (monotone,
// bit-exact). Decodes packed u16: sentinel -> (1e6 - h)^2 per reference.
// Block min/max written plainly to pmn/pmx[blockIdx].
// ---------------------------------------------------------------------------
__global__ void k_horiz(const unsigned short* __restrict__ gpk,
                        const int* __restrict__ hasfg_p, float* __restrict__ dt,
                        float* __restrict__ pmn, float* __restrict__ pmx) {
    __shared__ float sp[4][W_ + 2 * PAD_];
    __shared__ float sn[4][W_ + 2 * PAD_];
    __shared__ float bmn[4], bmx[4];
    int wave = threadIdx.x >> 6;
    int lane = threadIdx.x & 63;
    int row = blockIdx.x * 4 + wave;       // [0, NBC*H); all 4 rows same bc
    int bc = row >> 8;
    float* drow = dt + (size_t)row * W_;

    int hfl = 0;
    if (lane < 8) hfl = hasfg_p[bc * 8 + lane];
    bool hf = __any(hfl != 0);             // uniform across block (same bc)

    if (!hf) {
        #pragma unroll
        for (int i = 0; i < 4; ++i) drow[lane + 64 * i] = 0.0f;
        if (threadIdx.x == 0) { pmn[blockIdx.x] = 0.0f; pmx[blockIdx.x] = 0.0f; }
        return;
    }

    // init pads to +inf-ish
    float4 inf4 = make_float4(3.0e38f, 3.0e38f, 3.0e38f, 3.0e38f);
    ((float4*)&sp[wave][0])[lane]          = inf4;
    ((float4*)&sp[wave][PAD_ + W_])[lane]  = inf4;
    ((float4*)&sn[wave][0])[lane]          = inf4;
    ((float4*)&sn[wave][PAD_ + W_])[lane]  = inf4;

    // decode packed row -> sp/sn
    int hh = row & (H_ - 1);
    float s1 = (float)(1000000 - hh);
    float sent2 = s1 * s1;                 // == fl((1e6 - h)^2), reference-exact
    const ushort4 v4 = ((const ushort4*)(gpk + (size_t)row * W_))[lane];
    float4 fpv, fnv;
    {
        const unsigned short* vs = (const unsigned short*)&v4;
        float* fp = (float*)&fpv;
        float* fn = (float*)&fnv;
        #pragma unroll
        for (int q = 0; q < 4; ++q) {
            unsigned v = vs[q];
            unsigned d = v & 0x7FFFu;
            float g2 = (d == 0x7FFFu) ? sent2 : (float)(d * d);
            bool fg = (v & 0x8000u) != 0;
            fp[q] = fg ? g2 : 0.0f;
            fn[q] = fg ? 0.0f : g2;
        }
    }
    ((float4*)&sp[wave][PAD_])[lane] = fpv;
    ((float4*)&sn[wave][PAD_])[lane] = fnv;
    __syncthreads();

    float bp[4], bn[4];
    #pragma unroll
    for (int i = 0; i < 4; ++i) {
        int j = PAD_ + lane + 64 * i;
        bp[i] = sp[wave][j];
        bn[i] = sn[wave][j];
    }
    // neg transform expanding search (exact: remaining candidates >= r^2)
    for (int r = 1; r < W_; ++r) {
        float fr = (float)r;
        float r2 = fr * fr;
        float m = fmaxf(fmaxf(bn[0], bn[1]), fmaxf(bn[2], bn[3]));
        if (!__any(r2 < m)) break;
        #pragma unroll
        for (int i = 0; i < 4; ++i) {
            int j = PAD_ + lane + 64 * i;
            float v = fminf(sn[wave][j - r], sn[wave][j + r]);
            bn[i] = fminf(bn[i], fmaf(fr, fr, v));
        }
    }
    // pos transform expanding search
    for (int r = 1; r < W_; ++r) {
        float fr = (float)r;
        float r2 = fr * fr;
        float m = fmaxf(fmaxf(bp[0], bp[1]), fmaxf(bp[2], bp[3]));
        if (!__any(r2 < m)) break;
        #pragma unroll
        for (int i = 0; i < 4; ++i) {
            int j = PAD_ + lane + 64 * i;
            float v = fminf(sp[wave][j - r], sp[wave][j + r]);
            bp[i] = fminf(bp[i], fmaf(fr, fr, v));
        }
    }

    float dval[4], mn = 3.4e38f, mx = -3.4e38f;
    #pragma unroll
    for (int i = 0; i < 4; ++i) {
        dval[i] = sqrtf(bn[i]) - sqrtf(bp[i]);
        mn = fminf(mn, dval[i]);
        mx = fmaxf(mx, dval[i]);
    }
    #pragma unroll
    for (int off = 32; off; off >>= 1) {
        mn = fminf(mn, __shfl_xor(mn, off));
        mx = fmaxf(mx, __shfl_xor(mx, off));
    }
    if (lane == 0) { bmn[wave] = mn; bmx[wave] = mx; }
    __syncthreads();
    if (threadIdx.x == 0) {
        pmn[blockIdx.x] = fminf(fminf(bmn[0], bmn[1]), fminf(bmn[2], bmn[3]));
        pmx[blockIdx.x] = fmaxf(fmaxf(bmx[0], bmx[1]), fmaxf(bmx[2], bmx[3]));
    }
    #pragma unroll
    for (int i = 0; i < 4; ++i) drow[lane + 64 * i] = dval[i];
}

// ---------------------------------------------------------------------------
// K3: norm reduce (from pmn/pmx partials) + fused softmax over C + per-(b,c)
// partial sums. No atomics: plain store to accum_p. 256 blocks (32 x 8).
// ---------------------------------------------------------------------------
__global__ void k_sums(const float* __restrict__ logits, const float* __restrict__ dt,
                       const float* __restrict__ pmn, const float* __restrict__ pmx,
                       float* __restrict__ accum_p) {
    int b = blockIdx.y;
    int tid = threadIdx.x;
    __shared__ float snorm[C_ * 2];
    __shared__ float sI[4][C_], sP[4][C_], sD[4][C_];

    // norm: 16 threads per class reduce the 64 per-block partials
    if (tid < C_ * 16) {
        int c = tid >> 4, j = tid & 15;
        float mn = 3.4e38f, mx = -3.4e38f;
        #pragma unroll
        for (int q = 0; q < 4; ++q) {
            int idx = (b * C_ + c) * 64 + j * 4 + q;
            mn = fminf(mn, pmn[idx]);
            mx = fmaxf(mx, pmx[idx]);
        }
        #pragma unroll
        for (int off = 8; off; off >>= 1) {
            mn = fminf(mn, __shfl_xor(mn, off));
            mx = fmaxf(mx, __shfl_xor(mx, off));
        }
        if (j == 0) {
            snorm[c * 2]     = mn;
            snorm[c * 2 + 1] = 1.0f / (mx - mn + 1e-8f);
        }
    }
    __syncthreads();

    const float* lb = logits + (size_t)b * C_ * HW_;
    const float* db = dt + (size_t)b * C_ * HW_;

    float inter[C_], p2[C_], d2s[C_];
    #pragma unroll
    for (int c = 0; c < C_; ++c) { inter[c] = 0.f; p2[c] = 0.f; d2s[c] = 0.f; }

    for (int p = blockIdx.x * blockDim.x + tid; p < HW_;
         p += gridDim.x * blockDim.x) {
        float l[C_];
        float mxl = -3.4e38f;
        #pragma unroll
        for (int c = 0; c < C_; ++c) { l[c] = lb[c * HW_ + p]; mxl = fmaxf(mxl, l[c]); }
        float s = 0.f;
        #pragma unroll
        for (int c = 0; c < C_; ++c) { l[c] = expf(l[c] - mxl); s += l[c]; }
        float inv = 1.0f / s;
        #pragma unroll
        for (int c = 0; c < C_; ++c) {
            float pr = l[c] * inv;
            float dv = db[c * HW_ + p];
            float dn = (dv - snorm[c * 2]) * snorm[c * 2 + 1];
            inter[c] = fmaf(pr, dn, inter[c]);
            p2[c]    = fmaf(pr, pr, p2[c]);
            d2s[c]   = fmaf(dn, dn, d2s[c]);
        }
    }

    int lane = tid & 63;
    int wave = tid >> 6;
    #pragma unroll
    for (int c = 0; c < C_; ++c) {
        float a = inter[c], p = p2[c], d = d2s[c];
        #pragma unroll
        for (int off = 32; off; off >>= 1) {
            a += __shfl_down(a, off);
            p += __shfl_down(p, off);
            d += __shfl_down(d, off);
        }
        if (lane == 0) { sI[wave][c] = a; sP[wave][c] = p; sD[wave][c] = d; }
    }
    __syncthreads();
    if (tid < C_ * 3) {
        int c = tid % C_;
        int comp = tid / C_;
        float v = 0.f;
        #pragma unroll
        for (int w = 0; w < 4; ++w)
            v += (comp == 0) ? sI[w][c] : (comp == 1) ? sP[w][c] : sD[w][c];
        accum_p[(((size_t)b * SUMX_ + blockIdx.x) * C_ + c) * 3 + comp] = v;
    }
}

// ---------------------------------------------------------------------------
// K4: reduce partials, dice per (b,c), mean of (1 - dice) -> out[0]
// ---------------------------------------------------------------------------
__global__ void k_final(const float* __restrict__ accum_p, float* __restrict__ out) {
    int tid = threadIdx.x;                 // 128
    float v = 0.f;
    if (tid < NBC_) {
        int b = tid / C_, c = tid - b * C_;
        float inter = 0.f, p2 = 0.f, d2 = 0.f;
        for (int gx = 0; gx < SUMX_; ++gx) {
            size_t base = (((size_t)b * SUMX_ + gx) * C_ + c) * 3;
            inter += accum_p[base];
            p2    += accum_p[base + 1];
            d2    += accum_p[base + 2];
        }
        float dice = 2.0f * inter / (p2 + d2 + 1e-6f);
        v = 1.0f - dice;
    }
    #pragma unroll
    for (int off = 32; off; off >>= 1) v += __shfl_down(v, off);
    __shared__ float s2[2];
    if ((tid & 63) == 0) s2[tid >> 6] = v;
    __syncthreads();
    if (tid == 0) out[0] = (s2[0] + s2[1]) / (float)NBC_;
}

// ---------------------------------------------------------------------------
extern "C" void kernel_launch(void* const* d_in, const int* in_sizes, int n_in,
                              void* d_out, int out_size, void* d_ws, size_t ws_size,
                              hipStream_t stream) {
    const float* logits  = (const float*)d_in[0];
    const int*   targets = (const int*)d_in[1];
    float* out = (float*)d_out;

    // ws layout: dt f32[96*65536] | pmn f32[6144] | pmx f32[6144] |
    //            accum f32[8*32*12*3] | gpk u16[96*65536] | hasfg_p i32[768]
    float* dt    = (float*)d_ws;
    float* pmn   = dt + (size_t)NBC_ * HW_;
    float* pmx   = pmn + NBC_ * 64;
    float* accum = pmx + NBC_ * 64;
    unsigned short* gpk = (unsigned short*)(accum + (size_t)B_ * SUMX_ * C_ * 3);
    int* hasfg_p = (int*)(gpk + (size_t)NBC_ * HW_);

    k_vert<<<NBC_ * 8, 256, 0, stream>>>(targets, gpk, hasfg_p);
    k_horiz<<<NBC_ * H_ / 4, 256, 0, stream>>>(gpk, hasfg_p, dt, pmn, pmx);
    k_sums<<<dim3(SUMX_, B_), 256, 0, stream>>>(logits, dt, pmn, pmx, accum);
    k_final<<<1, 128, 0, stream>>>(accum, out);
}